// Round 6
// baseline (143.699 us; speedup 1.0000x reference)
//
#include <hip/hip_runtime.h>
#include <math.h>

// Weighted Kabsch: B=4096 batches, N=1024 points. SINGLE FUSED KERNEL.
// One wave per batch: 28 upfront coalesced float4 loads -> 16-scalar
// accumulate -> 64-lane butterfly allreduce -> ALL lanes redundantly run the
// 3x3 double-precision solve (wave-uniform branches) -> lane 0 writes R,t.
// No second launch, no sums round-trip, no LDS, no __syncthreads.

__global__ __launch_bounds__(256, 3) void wsvd_fused(
    const float* __restrict__ src, const float* __restrict__ corr,
    const float* __restrict__ wgt, float* __restrict__ out, int B)
{
    const int gtid = blockIdx.x * 256 + threadIdx.x;
    const int b = gtid >> 6;                  // one wave per batch
    const int lane = gtid & 63;

    const float4* W4 = reinterpret_cast<const float4*>(wgt  + (size_t)b * 1024);
    const float4* S4 = reinterpret_cast<const float4*>(src  + (size_t)b * 3072);
    const float4* C4 = reinterpret_cast<const float4*>(corr + (size_t)b * 3072);

    // 28 independent coalesced 16B loads (1 KB per wave per instr).
    float4 wv0 = W4[lane],        wv1 = W4[lane + 64],
           wv2 = W4[lane + 128],  wv3 = W4[lane + 192];
    float4 s00 = S4[lane],        s01 = S4[lane + 64],
           s02 = S4[lane + 128],  s03 = S4[lane + 192];
    float4 s10 = S4[lane + 256],  s11 = S4[lane + 320],
           s12 = S4[lane + 384],  s13 = S4[lane + 448];
    float4 s20 = S4[lane + 512],  s21 = S4[lane + 576],
           s22 = S4[lane + 640],  s23 = S4[lane + 704];
    float4 c00 = C4[lane],        c01 = C4[lane + 64],
           c02 = C4[lane + 128],  c03 = C4[lane + 192];
    float4 c10 = C4[lane + 256],  c11 = C4[lane + 320],
           c12 = C4[lane + 384],  c13 = C4[lane + 448];
    float4 c20 = C4[lane + 512],  c21 = C4[lane + 576],
           c22 = C4[lane + 640],  c23 = C4[lane + 704];

    float wsum = 0.f, ws0 = 0.f, ws1 = 0.f, ws2 = 0.f;
    float wc0 = 0.f, wc1 = 0.f, wc2 = 0.f;
    float m00 = 0.f, m01 = 0.f, m02 = 0.f;
    float m10 = 0.f, m11 = 0.f, m12 = 0.f;
    float m20 = 0.f, m21 = 0.f, m22 = 0.f;

#define PROC1(wv, a0, a1, a2, b0, b1, b2, f) { \
    float w_ = wv.f; \
    float t0 = w_ * a0.f, t1 = w_ * a1.f, t2 = w_ * a2.f; \
    wsum += w_; ws0 += t0; ws1 += t1; ws2 += t2; \
    wc0 += w_ * b0.f; wc1 += w_ * b1.f; wc2 += w_ * b2.f; \
    m00 += t0 * b0.f; m01 += t0 * b1.f; m02 += t0 * b2.f; \
    m10 += t1 * b0.f; m11 += t1 * b1.f; m12 += t1 * b2.f; \
    m20 += t2 * b0.f; m21 += t2 * b1.f; m22 += t2 * b2.f; }
#define PROCV(wv, a0, a1, a2, b0, b1, b2) \
    PROC1(wv, a0, a1, a2, b0, b1, b2, x) \
    PROC1(wv, a0, a1, a2, b0, b1, b2, y) \
    PROC1(wv, a0, a1, a2, b0, b1, b2, z) \
    PROC1(wv, a0, a1, a2, b0, b1, b2, w)

    PROCV(wv0, s00, s10, s20, c00, c10, c20)
    PROCV(wv1, s01, s11, s21, c01, c11, c21)
    PROCV(wv2, s02, s12, s22, c02, c12, c22)
    PROCV(wv3, s03, s13, s23, c03, c13, c23)
#undef PROCV
#undef PROC1

    // Butterfly allreduce: every lane ends with the full-batch totals.
#define BRED(v) { v += __shfl_xor(v, 1); v += __shfl_xor(v, 2); \
                  v += __shfl_xor(v, 4); v += __shfl_xor(v, 8); \
                  v += __shfl_xor(v, 16); v += __shfl_xor(v, 32); }
    BRED(wsum) BRED(ws0) BRED(ws1) BRED(ws2)
    BRED(wc0) BRED(wc1) BRED(wc2)
    BRED(m00) BRED(m01) BRED(m02)
    BRED(m10) BRED(m11) BRED(m12)
    BRED(m20) BRED(m21) BRED(m22)
#undef BRED

    // ---- Solve (all lanes redundantly; values are wave-uniform) ----
    double dwsum = wsum;
    double dws0 = ws0, dws1 = ws1, dws2 = ws2;
    double dwc0 = wc0, dwc1 = wc1, dwc2 = wc2;

    double inv = 1.0 / dwsum;
    double s2x = dws0 * inv, s2y = dws1 * inv, s2z = dws2 * inv;
    double c2x = dwc0 * inv, c2y = dwc1 * inv, c2z = dwc2 * inv;
    double h00 = (double)m00 - dws0 * dwc0 * inv, h01 = (double)m01 - dws0 * dwc1 * inv, h02 = (double)m02 - dws0 * dwc2 * inv;
    double h10 = (double)m10 - dws1 * dwc0 * inv, h11 = (double)m11 - dws1 * dwc1 * inv, h12 = (double)m12 - dws1 * dwc2 * inv;
    double h20 = (double)m20 - dws2 * dwc0 * inv, h21 = (double)m21 - dws2 * dwc1 * inv, h22 = (double)m22 - dws2 * dwc2 * inv;

    // A = H^T H (symmetric)
    double a00 = h00 * h00 + h10 * h10 + h20 * h20;
    double a11 = h01 * h01 + h11 * h11 + h21 * h21;
    double a22 = h02 * h02 + h12 * h12 + h22 * h22;
    double a01 = h00 * h01 + h10 * h11 + h20 * h21;
    double a02 = h00 * h02 + h10 * h12 + h20 * h22;
    double a12 = h01 * h02 + h11 * h12 + h21 * h22;

    // Jacobi eigensolve: A = V diag(l) V^T. All scalars, no indexed arrays.
    double v00 = 1.0, v01 = 0.0, v02 = 0.0;
    double v10 = 0.0, v11 = 1.0, v12 = 0.0;
    double v20 = 0.0, v21 = 0.0, v22 = 1.0;

#define ROT(app, aqq, apq, apr, aqr, vp0, vq0, vp1, vq1, vp2, vq2) { \
    double apq_ = apq; \
    double cc, ss, tt; \
    if (fabs(apq_) > 1e-300) { \
        double tau = (aqq - app) / (2.0 * apq_); \
        tt = copysign(1.0, tau) / (fabs(tau) + sqrt(1.0 + tau * tau)); \
        cc = 1.0 / sqrt(1.0 + tt * tt); ss = tt * cc; \
    } else { tt = 0.0; cc = 1.0; ss = 0.0; } \
    app -= tt * apq_; aqq += tt * apq_; apq = 0.0; \
    { double pr = apr, qr = aqr; apr = cc * pr - ss * qr; aqr = ss * pr + cc * qr; } \
    { double t0_ = vp0; vp0 = cc * t0_ - ss * vq0; vq0 = ss * t0_ + cc * vq0; } \
    { double t0_ = vp1; vp1 = cc * t0_ - ss * vq1; vq1 = ss * t0_ + cc * vq1; } \
    { double t0_ = vp2; vp2 = cc * t0_ - ss * vq2; vq2 = ss * t0_ + cc * vq2; } }

    for (int sweep = 0; sweep < 5; ++sweep) {
        ROT(a00, a11, a01, a02, a12, v00, v01, v10, v11, v20, v21)
        ROT(a00, a22, a02, a01, a12, v00, v02, v10, v12, v20, v22)
        ROT(a11, a22, a12, a01, a02, v01, v02, v11, v12, v21, v22)
    }
#undef ROT

    // sort eigenpairs descending (columns of V)
    double l0 = a00, l1 = a11, l2 = a22;
#define CSWAP(li, lj, x0, y0, x1, y1, x2, y2) if (li < lj) { double t_; \
    t_ = li; li = lj; lj = t_; t_ = x0; x0 = y0; y0 = t_; \
    t_ = x1; x1 = y1; y1 = t_; t_ = x2; x2 = y2; y2 = t_; }
    CSWAP(l0, l1, v00, v01, v10, v11, v20, v21)
    CSWAP(l0, l2, v00, v02, v10, v12, v20, v22)
    CSWAP(l1, l2, v01, v02, v11, v12, v21, v22)
#undef CSWAP

    // u0 = normalize(H v0)
    double u0x = h00 * v00 + h01 * v10 + h02 * v20;
    double u0y = h10 * v00 + h11 * v10 + h12 * v20;
    double u0z = h20 * v00 + h21 * v10 + h22 * v20;
    double n0 = sqrt(u0x * u0x + u0y * u0y + u0z * u0z);
    if (n0 > 1e-300) { double r = 1.0 / n0; u0x *= r; u0y *= r; u0z *= r; }
    else { u0x = 1.0; u0y = 0.0; u0z = 0.0; }

    // u1 = normalize(H v1 - (u0 . H v1) u0)
    double u1x = h00 * v01 + h01 * v11 + h02 * v21;
    double u1y = h10 * v01 + h11 * v11 + h12 * v21;
    double u1z = h20 * v01 + h21 * v11 + h22 * v21;
    double dp = u0x * u1x + u0y * u1y + u0z * u1z;
    u1x -= dp * u0x; u1y -= dp * u0y; u1z -= dp * u0z;
    double n1 = sqrt(u1x * u1x + u1y * u1y + u1z * u1z);
    if (n1 > 1e-300) { double r = 1.0 / n1; u1x *= r; u1y *= r; u1z *= r; }
    else {
        if (fabs(u0x) < 0.9) { u1x = 0.0; u1y = u0z; u1z = -u0y; }
        else                 { u1x = -u0z; u1y = 0.0; u1z = u0x; }
        double r = 1.0 / sqrt(u1x * u1x + u1y * u1y + u1z * u1z);
        u1x *= r; u1y *= r; u1z *= r;
    }

    // u2 = u0 x u1  (det(U) = +1 by construction)
    double u2x = u0y * u1z - u0z * u1y;
    double u2y = u0z * u1x - u0x * u1z;
    double u2z = u0x * u1y - u0y * u1x;

    double detV = v00 * (v11 * v22 - v12 * v21)
                - v01 * (v10 * v22 - v12 * v20)
                + v02 * (v10 * v21 - v11 * v20);
    double d = (detV >= 0.0) ? 1.0 : -1.0;

    // R[i][j] = v[i][0] u0[j] + v[i][1] u1[j] + d v[i][2] u2[j]
    double r00 = v00 * u0x + v01 * u1x + d * v02 * u2x;
    double r01 = v00 * u0y + v01 * u1y + d * v02 * u2y;
    double r02 = v00 * u0z + v01 * u1z + d * v02 * u2z;
    double r10 = v10 * u0x + v11 * u1x + d * v12 * u2x;
    double r11 = v10 * u0y + v11 * u1y + d * v12 * u2y;
    double r12 = v10 * u0z + v11 * u1z + d * v12 * u2z;
    double r20 = v20 * u0x + v21 * u1x + d * v22 * u2x;
    double r21 = v20 * u0y + v21 * u1y + d * v22 * u2y;
    double r22 = v20 * u0z + v21 * u1z + d * v22 * u2z;

    // t = c2 - R s2
    double tx = c2x - (r00 * s2x + r01 * s2y + r02 * s2z);
    double ty = c2y - (r10 * s2x + r11 * s2y + r12 * s2z);
    double tz = c2z - (r20 * s2x + r21 * s2y + r22 * s2z);

    if (lane == 0) {
        float* Ro = out + (size_t)b * 9;
        Ro[0] = (float)r00; Ro[1] = (float)r01; Ro[2] = (float)r02;
        Ro[3] = (float)r10; Ro[4] = (float)r11; Ro[5] = (float)r12;
        Ro[6] = (float)r20; Ro[7] = (float)r21; Ro[8] = (float)r22;
        float* To = out + (size_t)B * 9 + (size_t)b * 3;
        To[0] = (float)tx; To[1] = (float)ty; To[2] = (float)tz;
    }
}

extern "C" void kernel_launch(void* const* d_in, const int* in_sizes, int n_in,
                              void* d_out, int out_size, void* d_ws, size_t ws_size,
                              hipStream_t stream) {
    const float* src  = (const float*)d_in[0];
    const float* corr = (const float*)d_in[1];
    const float* wgt  = (const float*)d_in[2];
    float* out = (float*)d_out;

    const int N = 1024;                       // fixed by problem spec
    const int B = in_sizes[2] / N;            // weight is (B,1,N)

    wsvd_fused<<<B / 4, 256, 0, stream>>>(src, corr, wgt, out, B);  // 1 wave/batch
}

// Round 8
// 139.494 us; speedup vs baseline: 1.0301x; 1.0301x over previous
//
#include <hip/hip_runtime.h>
#include <math.h>

// Weighted Kabsch: B=4096 batches, N=1024 points. SINGLE FUSED KERNEL.
// TWO WAVES PER BATCH (8192 waves -> up to 24-32 waves/CU; R6 showed the
// memory phase is concurrency-limited at 16 waves/CU). Each wave: 14 upfront
// coalesced float4 loads over its half of the batch -> 16-scalar accumulate
// -> 64-lane shuffle reduce -> lane0 writes partials to LDS -> block sync ->
// first wave of each pair adds partner partials and runs the f64 solve with
// CHEAP MATH (f32-hw-seeded Newton rcp/rsqrt, no libm f64 div/sqrt).

__device__ __forceinline__ double drcp(double x) {
    // valid for |x| in f32 range (callers guarantee); full f64 accuracy
    double r = (double)(1.0f / (float)x);
    r = r * __fma_rn(-x, r, 2.0);
    r = r * __fma_rn(-x, r, 2.0);
    return r;
}
__device__ __forceinline__ double drsqrt(double x) {
    // x > ~1e-30 (callers guarantee)
    double r = (double)__frsqrt_rn((float)x);
    r = r * __fma_rn(-0.5 * x * r, r, 1.5);
    r = r * __fma_rn(-0.5 * x * r, r, 1.5);
    return r;
}

__global__ __launch_bounds__(256, 6) void wsvd_fused(
    const float* __restrict__ src, const float* __restrict__ corr,
    const float* __restrict__ wgt, float* __restrict__ out, int B)
{
    const int wave = threadIdx.x >> 6;
    const int lane = threadIdx.x & 63;
    const int b = blockIdx.x * 2 + (wave >> 1);   // 2 batches per block
    const int h = wave & 1;                       // which half of the batch

    const float4* W4 = reinterpret_cast<const float4*>(wgt  + (size_t)b * 1024);
    const float4* S4 = reinterpret_cast<const float4*>(src  + (size_t)b * 3072);
    const float4* C4 = reinterpret_cast<const float4*>(corr + (size_t)b * 3072);

    const int i0 = h * 128 + lane;                // 128 float4 per half-row
    const int i1 = i0 + 64;

    // 14 independent coalesced 16B loads.
    float4 wv0 = W4[i0],        wv1 = W4[i1];
    float4 s00 = S4[i0],        s01 = S4[i1];
    float4 s10 = S4[i0 + 256],  s11 = S4[i1 + 256];
    float4 s20 = S4[i0 + 512],  s21 = S4[i1 + 512];
    float4 c00 = C4[i0],        c01 = C4[i1];
    float4 c10 = C4[i0 + 256],  c11 = C4[i1 + 256];
    float4 c20 = C4[i0 + 512],  c21 = C4[i1 + 512];

    float wsum = 0.f, ws0 = 0.f, ws1 = 0.f, ws2 = 0.f;
    float wc0 = 0.f, wc1 = 0.f, wc2 = 0.f;
    float m00 = 0.f, m01 = 0.f, m02 = 0.f;
    float m10 = 0.f, m11 = 0.f, m12 = 0.f;
    float m20 = 0.f, m21 = 0.f, m22 = 0.f;

#define PROC1(wv, a0, a1, a2, b0, b1, b2, f) { \
    float w_ = wv.f; \
    float t0 = w_ * a0.f, t1 = w_ * a1.f, t2 = w_ * a2.f; \
    wsum += w_; ws0 += t0; ws1 += t1; ws2 += t2; \
    wc0 += w_ * b0.f; wc1 += w_ * b1.f; wc2 += w_ * b2.f; \
    m00 += t0 * b0.f; m01 += t0 * b1.f; m02 += t0 * b2.f; \
    m10 += t1 * b0.f; m11 += t1 * b1.f; m12 += t1 * b2.f; \
    m20 += t2 * b0.f; m21 += t2 * b1.f; m22 += t2 * b2.f; }
#define PROCV(wv, a0, a1, a2, b0, b1, b2) \
    PROC1(wv, a0, a1, a2, b0, b1, b2, x) \
    PROC1(wv, a0, a1, a2, b0, b1, b2, y) \
    PROC1(wv, a0, a1, a2, b0, b1, b2, z) \
    PROC1(wv, a0, a1, a2, b0, b1, b2, w)

    PROCV(wv0, s00, s10, s20, c00, c10, c20)
    PROCV(wv1, s01, s11, s21, c01, c11, c21)
#undef PROCV
#undef PROC1

    // Wave-level reduce (result valid at lane 0).
#define BRED(v) { v += __shfl_xor(v, 1); v += __shfl_xor(v, 2); \
                  v += __shfl_xor(v, 4); v += __shfl_xor(v, 8); \
                  v += __shfl_xor(v, 16); v += __shfl_xor(v, 32); }
    BRED(wsum) BRED(ws0) BRED(ws1) BRED(ws2)
    BRED(wc0) BRED(wc1) BRED(wc2)
    BRED(m00) BRED(m01) BRED(m02)
    BRED(m10) BRED(m11) BRED(m12)
    BRED(m20) BRED(m21) BRED(m22)
#undef BRED

    __shared__ float sm[4][16];
    if (lane == 0) {
        float* o = sm[wave];
        o[0] = wsum; o[1] = ws0; o[2] = ws1; o[3] = ws2;
        o[4] = wc0;  o[5] = wc1; o[6] = wc2; o[7] = m00;
        o[8] = m01;  o[9] = m02; o[10] = m10; o[11] = m11;
        o[12] = m12; o[13] = m20; o[14] = m21; o[15] = m22;
    }
    __syncthreads();
    if (h != 0) return;                        // second wave of pair done

    // Combine the two half-batch partials (broadcast reads, all lanes).
    const float* p0 = sm[wave];
    const float* p1 = sm[wave + 1];
    double dwsum = (double)p0[0] + p1[0];
    double dws0 = (double)p0[1] + p1[1], dws1 = (double)p0[2] + p1[2], dws2 = (double)p0[3] + p1[3];
    double dwc0 = (double)p0[4] + p1[4], dwc1 = (double)p0[5] + p1[5], dwc2 = (double)p0[6] + p1[6];
    double dm00 = (double)p0[7] + p1[7], dm01 = (double)p0[8] + p1[8], dm02 = (double)p0[9] + p1[9];
    double dm10 = (double)p0[10] + p1[10], dm11 = (double)p0[11] + p1[11], dm12 = (double)p0[12] + p1[12];
    double dm20 = (double)p0[13] + p1[13], dm21 = (double)p0[14] + p1[14], dm22 = (double)p0[15] + p1[15];

    double inv = drcp(dwsum);
    double s2x = dws0 * inv, s2y = dws1 * inv, s2z = dws2 * inv;
    double c2x = dwc0 * inv, c2y = dwc1 * inv, c2z = dwc2 * inv;
    double h00 = dm00 - dws0 * dwc0 * inv, h01 = dm01 - dws0 * dwc1 * inv, h02 = dm02 - dws0 * dwc2 * inv;
    double h10 = dm10 - dws1 * dwc0 * inv, h11 = dm11 - dws1 * dwc1 * inv, h12 = dm12 - dws1 * dwc2 * inv;
    double h20 = dm20 - dws2 * dwc0 * inv, h21 = dm21 - dws2 * dwc1 * inv, h22 = dm22 - dws2 * dwc2 * inv;

    // A = H^T H (symmetric)
    double a00 = h00 * h00 + h10 * h10 + h20 * h20;
    double a11 = h01 * h01 + h11 * h11 + h21 * h21;
    double a22 = h02 * h02 + h12 * h12 + h22 * h22;
    double a01 = h00 * h01 + h10 * h11 + h20 * h21;
    double a02 = h00 * h02 + h10 * h12 + h20 * h22;
    double a12 = h01 * h02 + h11 * h12 + h21 * h22;

    // Jacobi eigensolve with cheap math. Branches are wave-uniform.
    double v00 = 1.0, v01 = 0.0, v02 = 0.0;
    double v10 = 0.0, v11 = 1.0, v12 = 0.0;
    double v20 = 0.0, v21 = 0.0, v22 = 1.0;

#define ROT(app, aqq, apq, apr, aqr, vp0, vq0, vp1, vq1, vp2, vq2) { \
    double apq_ = apq; \
    if (fabs(apq_) > fmax(1e-35, 1e-15 * (fabs(app) + fabs(aqq)))) { \
        double tau = (aqq - app) * 0.5 * drcp(apq_); \
        double t2_ = 1.0 + tau * tau; \
        double sq_ = t2_ * drsqrt(t2_); \
        double tt = copysign(1.0, tau) * drcp(fabs(tau) + sq_); \
        double cc = drsqrt(1.0 + tt * tt); \
        double ss = tt * cc; \
        app -= tt * apq_; aqq += tt * apq_; apq = 0.0; \
        { double pr = apr, qr = aqr; apr = cc * pr - ss * qr; aqr = ss * pr + cc * qr; } \
        { double t0_ = vp0; vp0 = cc * t0_ - ss * vq0; vq0 = ss * t0_ + cc * vq0; } \
        { double t0_ = vp1; vp1 = cc * t0_ - ss * vq1; vq1 = ss * t0_ + cc * vq1; } \
        { double t0_ = vp2; vp2 = cc * t0_ - ss * vq2; vq2 = ss * t0_ + cc * vq2; } } }

    for (int sweep = 0; sweep < 5; ++sweep) {
        ROT(a00, a11, a01, a02, a12, v00, v01, v10, v11, v20, v21)
        ROT(a00, a22, a02, a01, a12, v00, v02, v10, v12, v20, v22)
        ROT(a11, a22, a12, a01, a02, v01, v02, v11, v12, v21, v22)
    }
#undef ROT

    // sort eigenpairs descending (columns of V)
    double l0 = a00, l1 = a11, l2 = a22;
#define CSWAP(li, lj, x0, y0, x1, y1, x2, y2) if (li < lj) { double t_; \
    t_ = li; li = lj; lj = t_; t_ = x0; x0 = y0; y0 = t_; \
    t_ = x1; x1 = y1; y1 = t_; t_ = x2; x2 = y2; y2 = t_; }
    CSWAP(l0, l1, v00, v01, v10, v11, v20, v21)
    CSWAP(l0, l2, v00, v02, v10, v12, v20, v22)
    CSWAP(l1, l2, v01, v02, v11, v12, v21, v22)
#undef CSWAP

    // u0 = normalize(H v0)
    double u0x = h00 * v00 + h01 * v10 + h02 * v20;
    double u0y = h10 * v00 + h11 * v10 + h12 * v20;
    double u0z = h20 * v00 + h21 * v10 + h22 * v20;
    double n0sq = u0x * u0x + u0y * u0y + u0z * u0z;
    if (n0sq > 1e-30) { double r = drsqrt(n0sq); u0x *= r; u0y *= r; u0z *= r; }
    else { u0x = 1.0; u0y = 0.0; u0z = 0.0; }

    // u1 = normalize(H v1 - (u0 . H v1) u0)
    double u1x = h00 * v01 + h01 * v11 + h02 * v21;
    double u1y = h10 * v01 + h11 * v11 + h12 * v21;
    double u1z = h20 * v01 + h21 * v11 + h22 * v21;
    double dp = u0x * u1x + u0y * u1y + u0z * u1z;
    u1x -= dp * u0x; u1y -= dp * u0y; u1z -= dp * u0z;
    double n1sq = u1x * u1x + u1y * u1y + u1z * u1z;
    if (n1sq > 1e-30) { double r = drsqrt(n1sq); u1x *= r; u1y *= r; u1z *= r; }
    else {
        if (fabs(u0x) < 0.9) { u1x = 0.0; u1y = u0z; u1z = -u0y; }
        else                 { u1x = -u0z; u1y = 0.0; u1z = u0x; }
        double r = drsqrt(u1x * u1x + u1y * u1y + u1z * u1z);
        u1x *= r; u1y *= r; u1z *= r;
    }

    // u2 = u0 x u1  (det(U) = +1 by construction)
    double u2x = u0y * u1z - u0z * u1y;
    double u2y = u0z * u1x - u0x * u1z;
    double u2z = u0x * u1y - u0y * u1x;

    double detV = v00 * (v11 * v22 - v12 * v21)
                - v01 * (v10 * v22 - v12 * v20)
                + v02 * (v10 * v21 - v11 * v20);
    double d = (detV >= 0.0) ? 1.0 : -1.0;

    // R[i][j] = v[i][0] u0[j] + v[i][1] u1[j] + d v[i][2] u2[j]
    double r00 = v00 * u0x + v01 * u1x + d * v02 * u2x;
    double r01 = v00 * u0y + v01 * u1y + d * v02 * u2y;
    double r02 = v00 * u0z + v01 * u1z + d * v02 * u2z;
    double r10 = v10 * u0x + v11 * u1x + d * v12 * u2x;
    double r11 = v10 * u0y + v11 * u1y + d * v12 * u2y;
    double r12 = v10 * u0z + v11 * u1z + d * v12 * u2z;
    double r20 = v20 * u0x + v21 * u1x + d * v22 * u2x;
    double r21 = v20 * u0y + v21 * u1y + d * v22 * u2y;
    double r22 = v20 * u0z + v21 * u1z + d * v22 * u2z;

    // t = c2 - R s2
    double tx = c2x - (r00 * s2x + r01 * s2y + r02 * s2z);
    double ty = c2y - (r10 * s2x + r11 * s2y + r12 * s2z);
    double tz = c2z - (r20 * s2x + r21 * s2y + r22 * s2z);

    if (lane == 0) {
        float* Ro = out + (size_t)b * 9;
        Ro[0] = (float)r00; Ro[1] = (float)r01; Ro[2] = (float)r02;
        Ro[3] = (float)r10; Ro[4] = (float)r11; Ro[5] = (float)r12;
        Ro[6] = (float)r20; Ro[7] = (float)r21; Ro[8] = (float)r22;
        float* To = out + (size_t)B * 9 + (size_t)b * 3;
        To[0] = (float)tx; To[1] = (float)ty; To[2] = (float)tz;
    }
}

extern "C" void kernel_launch(void* const* d_in, const int* in_sizes, int n_in,
                              void* d_out, int out_size, void* d_ws, size_t ws_size,
                              hipStream_t stream) {
    const float* src  = (const float*)d_in[0];
    const float* corr = (const float*)d_in[1];
    const float* wgt  = (const float*)d_in[2];
    float* out = (float*)d_out;

    const int N = 1024;                       // fixed by problem spec
    const int B = in_sizes[2] / N;            // weight is (B,1,N)

    wsvd_fused<<<B / 2, 256, 0, stream>>>(src, corr, wgt, out, B);  // 2 waves/batch
}